// Round 2
// baseline (149.186 us; speedup 1.0000x reference)
//
#include <hip/hip_runtime.h>
#include <math.h>

// The position/mask chain must replicate the numpy fp32 reference bit-exactly
// (no FMA contraction): the entry-face validity test (pos > -1) is knife-edge
// for every hitting ray. Sample math is u8-quantized and may contract.
#pragma clang fp contract(off)

#define DT 0.03125f
#define INV_DT 32.0f
#define NSTEPS 111

#if defined(__has_builtin)
#if __has_builtin(__builtin_amdgcn_udot4)
#define HAVE_UDOT4 1
#endif
#endif

__device__ __forceinline__ unsigned udot4(unsigned a, unsigned b) {
#ifdef HAVE_UDOT4
    return __builtin_amdgcn_udot4(a, b, 0u, false);
#else
    return (a & 0xffu) * (b & 0xffu)
         + ((a >> 8) & 0xffu) * ((b >> 8) & 0xffu)
         + ((a >> 16) & 0xffu) * ((b >> 16) & 0xffu)
         + ((a >> 24) & 0xffu) * ((b >> 24) & 0xffu);
#endif
}

// ---------------- u8 stencil-pair packing ----------------
// Entry (z,y,x) = 16B = 4 dwords (r,g,b,sigma); dword bytes:
//   [c(x0,y0), c(x1,y0), c(x0,y1), c(x1,y1)]  (x1=min(x+1,D-1), y1=min(y+1,D-1))
// Trilinear stencil = entry at z0 + entry at z0+1: 2 gathers/step.

__device__ __forceinline__ unsigned q8(float v) {
    return __float2uint_rn(fminf(fmaxf(v, 0.0f), 1.0f) * 255.0f);
}

// R12: row-sharing repack. Each voxel is loaded and quantized exactly ONCE,
// u8 rows staged in LDS, stencil-pair dwords assembled from LDS bytes. Only
// one extra row per block comes from global (+12.5%). ~142 MB total traffic
// (67 read + 8 extra + 67 write) -> near the BW floor for this layout.
template <int DD>
__global__ __launch_bounds__(256) void repack_u8x4_rowshare_kernel(
        const float* __restrict__ vol, uint4* __restrict__ out, long spatial) {
    constexpr int D = DD;
    constexpr int TPR = D / 4;       // threads per row (chunks of 4 voxels)
    constexpr int R = 1024 / D;      // full rows covered per block
    constexpr int ZS = D * D;

    int t = threadIdx.x;
    long b = blockIdx.y;
    long s_base = (long)blockIdx.x << 10;      // first voxel of this block
    int z = (int)(s_base / ZS);
    int rem = (int)(s_base - (long)z * ZS);
    int y0 = rem / D;                          // rem % D == 0 by construction
    int yl = t / TPR;                          // local row 0..R-1
    int x0 = (t - yl * TPR) * 4;

    const float* base = vol + b * 4 * spatial + (long)z * ZS;

    // Stage quantized rows once: stage[ch][row][word-of-4-bytes].
    __shared__ unsigned stage[4][R + 1][TPR];
    #pragma unroll
    for (int ci = 0; ci < 4; ++ci) {
        const float* p = base + (long)ci * spatial + (y0 + yl) * D + x0;
        float4 v = *(const float4*)p;
        stage[ci][yl][x0 >> 2] =
            q8(v.x) | (q8(v.y) << 8) | (q8(v.z) << 16) | (q8(v.w) << 24);
    }
    if (t < TPR) {                             // one extra row: y0+R (clamped)
        int ye = y0 + R; if (ye > D - 1) ye = D - 1;   // clamp == duplicate of
        #pragma unroll                                 // last row: matches y1
        for (int ci = 0; ci < 4; ++ci) {               // clamp semantics
            const float* p = base + (long)ci * spatial + ye * D + t * 4;
            float4 v = *(const float4*)p;
            stage[ci][R][t] =
                q8(v.x) | (q8(v.y) << 8) | (q8(v.z) << 16) | (q8(v.w) << 24);
        }
    }
    __syncthreads();

    int w = x0 >> 2;
    bool last = (x0 + 4 >= D);                 // row end: x+1 clamps to D-1
    uint4 e[4];
    #pragma unroll
    for (int ci = 0; ci < 4; ++ci) {
        unsigned wA0 = stage[ci][yl][w];
        unsigned wB0 = stage[ci][yl + 1][w];
        unsigned a4 = last ? (wA0 >> 24) : (stage[ci][yl][w + 1] & 0xffu);
        unsigned b4 = last ? (wB0 >> 24) : (stage[ci][yl + 1][w + 1] & 0xffu);
        unsigned a[5] = {wA0 & 0xffu, (wA0 >> 8) & 0xffu,
                         (wA0 >> 16) & 0xffu, wA0 >> 24, a4};
        unsigned bb[5] = {wB0 & 0xffu, (wB0 >> 8) & 0xffu,
                          (wB0 >> 16) & 0xffu, wB0 >> 24, b4};
        #pragma unroll
        for (int k = 0; k < 4; ++k) {
            ((unsigned*)&e[k])[ci] =
                a[k] | (a[k + 1] << 8) | (bb[k] << 16) | (bb[k + 1] << 24);
        }
    }

    // LDS transpose -> fully coalesced 16B/lane stores.
    __shared__ uint4 lds[4 * 257];
    #pragma unroll
    for (int j = 0; j < 4; ++j) lds[j * 257 + t] = e[j];
    __syncthreads();
    uint4* o = out + b * spatial + ((long)blockIdx.x << 10);
    #pragma unroll
    for (int k = 0; k < 4; ++k) {
        o[k * 256 + t] = lds[(t & 3) * 257 + k * 64 + (t >> 2)];
    }
}

// Repack with shfl neighbor fetch + LDS-staged COALESCED stores (fallback for
// D != 128 meeting the old validity conditions).
__global__ __launch_bounds__(256) void repack_u8x4_lds_kernel(
        const float* __restrict__ vol, uint4* __restrict__ out,
        long spatial, int D) {
    long chunk = (long)blockIdx.x * 256 + threadIdx.x;
    long b = blockIdx.y;
    long s = chunk << 2;
    int zs = D * D;
    int z = (int)(s / zs);
    int rem = (int)(s - (long)z * zs);
    int y = rem / D;
    int x0 = rem - y * D;           // chunk never straddles a row (D%4==0)
    int y1 = (y < D - 1) ? y + 1 : y;
    bool last = (x0 + 4 >= D);      // row-end: x+1 clamps to D-1 (= va.w)

    const float* base = vol + b * 4 * spatial;
    uint4 e[4];
    #pragma unroll
    for (int ci = 0; ci < 4; ++ci) {
        const float* pa = base + (long)ci * spatial + (long)z * zs + y * D + x0;
        const float* pb = base + (long)ci * spatial + (long)z * zs + y1 * D + x0;
        float4 va = *(const float4*)pa;
        float4 vb = *(const float4*)pb;
        float na_sh = __shfl_down(va.x, 1, 64);   // lane i+1's first element
        float nb_sh = __shfl_down(vb.x, 1, 64);
        float na = last ? va.w : na_sh;           // row-end lanes override (also
        float nb = last ? vb.w : nb_sh;           // covers wave-boundary lanes)
        float ra[5] = {va.x, va.y, va.z, va.w, na};
        float rb[5] = {vb.x, vb.y, vb.z, vb.w, nb};
        #pragma unroll
        for (int k = 0; k < 4; ++k) {
            unsigned d = q8(ra[k]) | (q8(ra[k + 1]) << 8) |
                         (q8(rb[k]) << 16) | (q8(rb[k + 1]) << 24);
            ((unsigned*)&e[k])[ci] = d;
        }
    }

    __shared__ uint4 lds[4 * 257];
    int t = threadIdx.x;
    #pragma unroll
    for (int j = 0; j < 4; ++j) lds[j * 257 + t] = e[j];
    __syncthreads();
    uint4* o = out + b * spatial + ((long)blockIdx.x << 10);
    #pragma unroll
    for (int k = 0; k < 4; ++k) {
        o[k * 256 + t] = lds[(t & 3) * 257 + k * 64 + (t >> 2)];
    }
}

// Fast repack without shfl/LDS (scalar neighbor loads). Requires D % 4 == 0.
__global__ __launch_bounds__(256) void repack_u8x4_kernel(const float* __restrict__ vol,
                                                          uint4* __restrict__ out,
                                                          long spatial, int D) {
    long chunk = (long)blockIdx.x * blockDim.x + threadIdx.x;
    long nchunks = spatial >> 2;
    if (chunk >= nchunks) return;
    long b = blockIdx.y;
    long s = chunk << 2;
    int zs = D * D;
    int z = (int)(s / zs);
    int rem = (int)(s - (long)z * zs);
    int y = rem / D;
    int x0 = rem - y * D;
    int y1 = (y < D - 1) ? y + 1 : y;

    const float* base = vol + b * 4 * spatial;
    uint4 e[4];
    #pragma unroll
    for (int ci = 0; ci < 4; ++ci) {
        const float* pa = base + (long)ci * spatial + (long)z * zs + y * D + x0;
        const float* pb = base + (long)ci * spatial + (long)z * zs + y1 * D + x0;
        float4 va = *(const float4*)pa;
        float4 vb = *(const float4*)pb;
        bool last = (x0 + 4 >= D);
        float na = last ? pa[3] : pa[4];
        float nb = last ? pb[3] : pb[4];
        float ra[5] = {va.x, va.y, va.z, va.w, na};
        float rb[5] = {vb.x, vb.y, vb.z, vb.w, nb};
        #pragma unroll
        for (int k = 0; k < 4; ++k) {
            unsigned d = q8(ra[k]) | (q8(ra[k + 1]) << 8) |
                         (q8(rb[k]) << 16) | (q8(rb[k + 1]) << 24);
            ((unsigned*)&e[k])[ci] = d;
        }
    }
    uint4* o = out + b * spatial + s;
    o[0] = e[0]; o[1] = e[1]; o[2] = e[2]; o[3] = e[3];
}

// Generic repack: one entry per thread (any D).
__global__ __launch_bounds__(256) void repack_u8_kernel(const float* __restrict__ vol,
                                                        uint4* __restrict__ out,
                                                        long total, long spatial, int D) {
    long idx = (long)blockIdx.x * blockDim.x + threadIdx.x;
    if (idx >= total) return;
    long b = idx / spatial;
    long s = idx - b * spatial;
    int zs = D * D;
    int z = (int)(s / zs);
    int rem = (int)(s - (long)z * zs);
    int y = rem / D;
    int x = rem - y * D;
    int x1 = (x < D - 1) ? x + 1 : x;
    int y1 = (y < D - 1) ? y + 1 : y;
    const float* base = vol + b * 4 * spatial;
    uint4 e;
    #pragma unroll
    for (int ci = 0; ci < 4; ++ci) {
        const float* p = base + (long)ci * spatial + (long)z * zs;
        unsigned d = q8(p[y * D + x]) | (q8(p[y * D + x1]) << 8) |
                     (q8(p[y1 * D + x]) << 16) | (q8(p[y1 * D + x1]) << 24);
        ((unsigned*)&e)[ci] = d;
    }
    out[idx] = e;
}

// ---------------- shared ray setup (bit-exact) ----------------

struct Ray {
    float posx, posy, posz;
    float stx, sty, stz;
    int n;   // conservative bound: steps >= n are provably invalid
};

__device__ __forceinline__ Ray ray_setup(const float* __restrict__ camrot,
                                         const float* __restrict__ campos,
                                         const float* __restrict__ focal,
                                         const float* __restrict__ princpt,
                                         const float* __restrict__ pixelcoords,
                                         int b, int y, int x, int H, int W) {
#pragma clang fp contract(off)
    long pidx = (((long)b * H + y) * W + x) * 2;
    float px = pixelcoords[pidx];
    float py = pixelcoords[pidx + 1];
    const float* R = camrot + b * 9;
    float cpx = campos[b * 3 + 0], cpy = campos[b * 3 + 1], cpz = campos[b * 3 + 2];
    float flx = focal[b * 2 + 0], fly = focal[b * 2 + 1];
    float prx = princpt[b * 2 + 0], pry = princpt[b * 2 + 1];

    float rx = (px - prx) / flx;
    float ry = (py - pry) / fly;
    float rz = 1.0f;
    float dx = R[0] * rx + R[3] * ry + R[6] * rz;
    float dy = R[1] * rx + R[4] * ry + R[7] * rz;
    float dz = R[2] * rx + R[5] * ry + R[8] * rz;
    float ss = dx * dx;
    ss = ss + dy * dy;
    ss = ss + dz * dz;
    float nrm = sqrtf(ss);
    dx = dx / nrm; dy = dy / nrm; dz = dz / nrm;

    float t1x = (-1.0f - cpx) / dx, t2x = (1.0f - cpx) / dx;
    float t1y = (-1.0f - cpy) / dy, t2y = (1.0f - cpy) / dy;
    float t1z = (-1.0f - cpz) / dz, t2z = (1.0f - cpz) / dz;
    float tmin = fmaxf(fminf(t1x, t2x), fmaxf(fminf(t1y, t2y), fminf(t1z, t2z)));
    float tmax = fminf(fmaxf(t1x, t2x), fminf(fmaxf(t1y, t2y), fmaxf(t1z, t2z)));
    bool hit = tmin < tmax;
    float t0 = fmaxf(hit ? tmin : 0.0f, 0.0f);

    Ray r;
    r.posx = cpx + dx * t0;
    r.posy = cpy + dy * t0;
    r.posz = cpz + dz * t0;
    r.stx = dx * DT; r.sty = dy * DT; r.stz = dz * DT;

    // valid step s needs t0 + s*DT < tmax; +4 slack dwarfs fp drift over <=111
    // rounded adds. NaN span -> fminf selects NSTEPS (conservative). Steps in
    // [n, NSTEPS) are provably invalid (mask would be 0) so skipping is exact.
    float span = (tmax - t0) * INV_DT + 4.0f;
    span = fminf(span, (float)NSTEPS);
    r.n = (hit && span > 0.0f) ? (int)span : 0;
    return r;
}

// ---------------- march: u8 stencil-pair volume + v_dot4 sampling ----------
// (Single ray/thread. Do NOT re-attempt intra-thread pipelining or multi-ray
//  ILP — the scheduler collapses the buffers and serializes; measured 4x in
//  R3/R4/R6/R10.)
//
// R13: 8x8 blocks (one wave per block). 2048 blocks -> 8 blocks/CU with
// dynamic rebalancing (was 2 blocks/CU static = full tail exposure), and the
// wave footprint is a compact 8x8 pixel square (was 16x4 strip) -> rays in a
// wave are more homogeneous -> collective saturation-exit fires earlier and
// per-step L1 footprint shrinks.
//
// R13 VALU trim (masked-lane math only; bit-exact chain untouched):
//  - floorf -> int truncation: inside lanes have g in (0,127) where trunc ==
//    floor; outside lanes are masked and the index clamp makes them identical.
//  - fx/fy/fz clamps dropped: when m==1, f is naturally in [0,1); when m==0
//    the sample is multiplied by 0. Weights use unsigned arithmetic so
//    masked-lane garbage stays defined (no signed overflow UB).

#define MARCH_STEP                                                             \
    {                                                                          \
        bool inside = (pxx > -1.0f) && (pxx < 1.0f) && (pyy > -1.0f) &&        \
                      (pyy < 1.0f) && (pzz > -1.0f) && (pzz < 1.0f);           \
        float m = inside ? 1.0f : 0.0f;                                        \
        float gx, gy, gz;                                                      \
        {                                                                      \
            _Pragma("clang fp contract(fast)")                                 \
            gx = pxx * gsc + gsc;                                              \
            gy = pyy * gsc + gsc;                                              \
            gz = pzz * gsc + gsc;                                              \
        }                                                                      \
        int ix = (int)gx; ix = min(max(ix, 0), D - 2);                         \
        int iy = (int)gy; iy = min(max(iy, 0), D - 2);                         \
        int iz = (int)gz; iz = min(max(iz, 0), D - 2);                         \
        float fx = gx - (float)ix;                                             \
        float fy = gy - (float)iy;                                             \
        float fz = gz - (float)iz;                                             \
        unsigned wx1 = (unsigned)(int)(fx * 255.0f + 0.5f);                    \
        unsigned wy1 = (unsigned)(int)(fy * 255.0f + 0.5f);                    \
        unsigned wx0 = 255u - wx1, wy0 = 255u - wy1;                           \
        unsigned p00 = ((wx0 * wy0 + 128u) >> 8) & 0xffu;                      \
        unsigned p10 = ((wx1 * wy0 + 128u) >> 8) & 0xffu;                      \
        unsigned p01 = ((wx0 * wy1 + 128u) >> 8) & 0xffu;                      \
        unsigned p11 = ((wx1 * wy1 + 128u) >> 8) & 0xffu;                      \
        unsigned wp = p00 | (p10 << 8) | (p01 << 16) | (p11 << 24);            \
        const uint4* p_ = vp + (iz * zs + iy * D + ix);                        \
        uint4 A = p_[0];                                                       \
        uint4 Bv = p_[zs];                                                     \
        float rA = (float)udot4(A.x, wp), rB = (float)udot4(Bv.x, wp);         \
        float gA = (float)udot4(A.y, wp), gB = (float)udot4(Bv.y, wp);         \
        float bA = (float)udot4(A.z, wp), bB = (float)udot4(Bv.z, wp);         \
        float sA = (float)udot4(A.w, wp), sB = (float)udot4(Bv.w, wp);         \
        float rS, gS, bS, sw;                                                  \
        {                                                                      \
            _Pragma("clang fp contract(fast)")                                 \
            rS = rA + fz * (rB - rA);                                          \
            gS = gA + fz * (gB - gA);                                          \
            bS = bA + fz * (bB - bA);                                          \
            sw = (sA + fz * (sB - sA)) * inv;                                  \
        }                                                                      \
        float contrib = (fminf(alpha + sw * DT, 1.0f) - alpha) * m;            \
        {                                                                      \
            _Pragma("clang fp contract(fast)")                                 \
            accr = accr + rS * contrib;                                        \
            accg = accg + gS * contrib;                                        \
            accb = accb + bS * contrib;                                        \
        }                                                                      \
        alpha = alpha + contrib;                                               \
        pxx = pxx + stx; pyy = pyy + sty; pzz = pzz + stz;                     \
    }

template <int DD>
__global__ __launch_bounds__(64) void raymarch_dot_kernel(
        const float* __restrict__ camrot, const float* __restrict__ campos,
        const float* __restrict__ focal, const float* __restrict__ princpt,
        const float* __restrict__ pixelcoords, const uint4* __restrict__ vol,
        float* __restrict__ out, int B, int H, int W, int Drt) {
#pragma clang fp contract(off)
    const int D = (DD > 0) ? DD : Drt;
    int x = blockIdx.x * 8 + threadIdx.x;
    int y = blockIdx.y * 8 + threadIdx.y;
    int b = blockIdx.z;
    if (x >= W || y >= H) return;

    Ray r = ray_setup(camrot, campos, focal, princpt, pixelcoords, b, y, x, H, W);

    float accr = 0.0f, accg = 0.0f, accb = 0.0f, alpha = 0.0f;
    const float gsc = 0.5f * (float)(D - 1);        // g = pos*gsc + gsc
    const float inv = 1.0f / (255.0f * 255.0f);
    const int zs = D * D;
    const uint4* vp = vol + (long)b * ((long)zs * D);
    float pxx = r.posx, pyy = r.posy, pzz = r.posz;
    float stx = r.stx, sty = r.sty, stz = r.stz;

    int s = 0;
    int nb = r.n & ~3;
    while (s < nb) {
        #pragma unroll
        for (int u = 0; u < 4; ++u) { MARCH_STEP; ++s; }
        if (alpha == 1.0f) break;               // saturated: contrib==0 forever
    }
    if (alpha != 1.0f) {
        for (; s < r.n; ++s) { MARCH_STEP; }
    }

    long hw = (long)H * W;
    long o = (long)b * 4 * hw + (long)y * W + x;
    out[o] = accr * inv;
    out[o + hw] = accg * inv;
    out[o + 2 * hw] = accb * inv;
    out[o + 3 * hw] = alpha;
}

// ---------------- fallback: whole-ray march on original fp32 layout ----------

__global__ __launch_bounds__(256) void raymarch_simple_kernel(
        const float* __restrict__ camrot, const float* __restrict__ campos,
        const float* __restrict__ focal, const float* __restrict__ princpt,
        const float* __restrict__ pixelcoords, const float* __restrict__ vol,
        float* __restrict__ out, int B, int H, int W, int D) {
#pragma clang fp contract(off)
    int x = blockIdx.x * blockDim.x + threadIdx.x;
    int y = blockIdx.y * blockDim.y + threadIdx.y;
    int b = blockIdx.z;
    if (x >= W || y >= H) return;

    Ray r = ray_setup(camrot, campos, focal, princpt, pixelcoords, b, y, x, H, W);

    float accr = 0.0f, accg = 0.0f, accb = 0.0f, alpha = 0.0f;
    float gmax = (float)(D - 1);
    long spatial = (long)D * D * D;
    long zstride = (long)D * D;
    const float* vb = vol + (long)b * 4 * spatial;
    float pxx = r.posx, pyy = r.posy, pzz = r.posz;

    for (int s = 0; s < r.n; ++s) {
        bool inside = (pxx > -1.0f) && (pxx < 1.0f) && (pyy > -1.0f) &&
                      (pyy < 1.0f) && (pzz > -1.0f) && (pzz < 1.0f);
        float m = inside ? 1.0f : 0.0f;
        float gx = fminf(fmaxf((pxx + 1.0f) * 0.5f * gmax, 0.0f), gmax);
        float gy = fminf(fmaxf((pyy + 1.0f) * 0.5f * gmax, 0.0f), gmax);
        float gz = fminf(fmaxf((pzz + 1.0f) * 0.5f * gmax, 0.0f), gmax);
        int ix0 = (int)floorf(gx); if (ix0 > D - 2) ix0 = D - 2;
        int iy0 = (int)floorf(gy); if (iy0 > D - 2) iy0 = D - 2;
        int iz0 = (int)floorf(gz); if (iz0 > D - 2) iz0 = D - 2;
        float fx = gx - (float)ix0;
        float fy = gy - (float)iy0;
        float fz = gz - (float)iz0;

        long s000 = (long)iz0 * zstride + (long)iy0 * D + ix0;
        float c[8][4];
        const long offs[8] = {s000, s000 + 1, s000 + D, s000 + D + 1,
                              s000 + zstride, s000 + zstride + 1,
                              s000 + zstride + D, s000 + zstride + D + 1};
        #pragma unroll
        for (int k = 0; k < 8; ++k) {
            c[k][0] = vb[offs[k]];
            c[k][1] = vb[offs[k] + spatial];
            c[k][2] = vb[offs[k] + 2 * spatial];
            c[k][3] = vb[offs[k] + 3 * spatial];
        }
        float wa = 1.0f - fx, wb = 1.0f - fy, wc = 1.0f - fz;
        float samp[4];
        #pragma unroll
        for (int ci = 0; ci < 4; ++ci) {
            float c00 = c[0][ci] * wa + c[1][ci] * fx;
            float c01 = c[2][ci] * wa + c[3][ci] * fx;
            float c10 = c[4][ci] * wa + c[5][ci] * fx;
            float c11 = c[6][ci] * wa + c[7][ci] * fx;
            float c0 = c00 * wb + c01 * fy;
            float c1 = c10 * wb + c11 * fy;
            samp[ci] = c0 * wc + c1 * fz;
        }
        float contrib = (fminf(alpha + samp[3] * DT, 1.0f) - alpha) * m;
        accr = accr + samp[0] * contrib;
        accg = accg + samp[1] * contrib;
        accb = accb + samp[2] * contrib;
        alpha = alpha + contrib;
        pxx = pxx + r.stx; pyy = pyy + r.sty; pzz = pzz + r.stz;
    }

    long hw = (long)H * W;
    long o = (long)b * 4 * hw + (long)y * W + x;
    out[o] = accr;
    out[o + hw] = accg;
    out[o + 2 * hw] = accb;
    out[o + 3 * hw] = alpha;
}

extern "C" void kernel_launch(void* const* d_in, const int* in_sizes, int n_in,
                              void* d_out, int out_size, void* d_ws, size_t ws_size,
                              hipStream_t stream) {
    const float* camrot = (const float*)d_in[0];
    const float* campos = (const float*)d_in[1];
    const float* focal = (const float*)d_in[2];
    const float* princpt = (const float*)d_in[3];
    const float* pixelcoords = (const float*)d_in[4];
    const float* volume = (const float*)d_in[5];
    float* out = (float*)d_out;

    int B = in_sizes[0] / 9;
    long spatial = (long)in_sizes[5] / (B * 4);  // D^3
    int D = (int)lround(cbrt((double)spatial));
    while ((long)D * D * D > spatial) D--;
    while ((long)(D + 1) * (D + 1) * (D + 1) <= spatial) D++;
    long hw = (long)in_sizes[4] / (B * 2);
    int H = (int)lround(sqrt((double)hw));
    int W = H;

    size_t vol_bytes = (size_t)B * spatial * sizeof(uint4);

    if (ws_size >= vol_bytes && D >= 2) {
        uint4* vol8 = (uint4*)d_ws;
        long nchunks = spatial >> 2;
        bool rowshare_ok = (D == 128) && ((nchunks % 256) == 0);
        bool lds_ok = ((D & 3) == 0) && ((64 % (D / 4)) == 0) &&
                      ((nchunks % 256) == 0);
        if (rowshare_ok) {
            dim3 rgrd((unsigned)(nchunks / 256), B, 1);
            repack_u8x4_rowshare_kernel<128><<<rgrd, dim3(256), 0, stream>>>(
                volume, vol8, spatial);
        } else if (lds_ok) {
            dim3 rgrd((unsigned)(nchunks / 256), B, 1);
            repack_u8x4_lds_kernel<<<rgrd, dim3(256), 0, stream>>>(volume, vol8,
                                                                   spatial, D);
        } else if ((D & 3) == 0) {
            dim3 rgrd((unsigned)((nchunks + 255) / 256), B, 1);
            repack_u8x4_kernel<<<rgrd, dim3(256), 0, stream>>>(volume, vol8, spatial, D);
        } else {
            long total = (long)B * spatial;
            repack_u8_kernel<<<dim3((unsigned)((total + 255) / 256)), dim3(256), 0,
                               stream>>>(volume, vol8, total, spatial, D);
        }
        dim3 blk(8, 8, 1);
        dim3 grd((W + 7) / 8, (H + 7) / 8, B);
        if (D == 128) {
            raymarch_dot_kernel<128><<<grd, blk, 0, stream>>>(
                camrot, campos, focal, princpt, pixelcoords, vol8, out, B, H, W, D);
        } else {
            raymarch_dot_kernel<0><<<grd, blk, 0, stream>>>(
                camrot, campos, focal, princpt, pixelcoords, vol8, out, B, H, W, D);
        }
    } else {
        dim3 blk(16, 16, 1);
        dim3 grd((W + 15) / 16, (H + 15) / 16, B);
        raymarch_simple_kernel<<<grd, blk, 0, stream>>>(camrot, campos, focal, princpt,
                                                        pixelcoords, volume,
                                                        out, B, H, W, D);
    }
}

// Round 3
// 136.080 us; speedup vs baseline: 1.0963x; 1.0963x over previous
//
#include <hip/hip_runtime.h>
#include <math.h>

// The position/mask chain must replicate the numpy fp32 reference bit-exactly
// (no FMA contraction): the entry-face validity test (pos > -1) is knife-edge
// for every hitting ray. Sample math is u8-quantized and may contract.
#pragma clang fp contract(off)

#define DT 0.03125f
#define INV_DT 32.0f
#define NSTEPS 111

#if defined(__has_builtin)
#if __has_builtin(__builtin_amdgcn_udot4)
#define HAVE_UDOT4 1
#endif
#endif

__device__ __forceinline__ unsigned udot4(unsigned a, unsigned b) {
#ifdef HAVE_UDOT4
    return __builtin_amdgcn_udot4(a, b, 0u, false);
#else
    return (a & 0xffu) * (b & 0xffu)
         + ((a >> 8) & 0xffu) * ((b >> 8) & 0xffu)
         + ((a >> 16) & 0xffu) * ((b >> 16) & 0xffu)
         + ((a >> 24) & 0xffu) * ((b >> 24) & 0xffu);
#endif
}

typedef unsigned u32x4 __attribute__((ext_vector_type(4)));

// ---------------- u8 stencil-pair packing ----------------
// Entry (z,y,x) = 16B = 4 dwords (r,g,b,sigma); dword bytes:
//   [c(x0,y0), c(x1,y0), c(x0,y1), c(x1,y1)]  (x1=min(x+1,D-1), y1=min(y+1,D-1))
// Trilinear stencil = entry at z0 + entry at z0+1: 2 gathers/step.

__device__ __forceinline__ unsigned q8(float v) {
    return __float2uint_rn(fminf(fmaxf(v, 0.0f), 1.0f) * 255.0f);
}

// R12: row-sharing repack. Each voxel is loaded and quantized exactly ONCE,
// u8 rows staged in LDS, stencil-pair dwords assembled from LDS bytes. Only
// one extra row per block comes from global (+12.5%). ~142 MB total traffic
// -> near the BW floor for this layout.
template <int DD>
__global__ __launch_bounds__(256) void repack_u8x4_rowshare_kernel(
        const float* __restrict__ vol, uint4* __restrict__ out, long spatial) {
    constexpr int D = DD;
    constexpr int TPR = D / 4;       // threads per row (chunks of 4 voxels)
    constexpr int R = 1024 / D;      // full rows covered per block
    constexpr int ZS = D * D;

    int t = threadIdx.x;
    long b = blockIdx.y;
    long s_base = (long)blockIdx.x << 10;      // first voxel of this block
    int z = (int)(s_base / ZS);
    int rem = (int)(s_base - (long)z * ZS);
    int y0 = rem / D;                          // rem % D == 0 by construction
    int yl = t / TPR;                          // local row 0..R-1
    int x0 = (t - yl * TPR) * 4;

    const float* base = vol + b * 4 * spatial + (long)z * ZS;

    __shared__ unsigned stage[4][R + 1][TPR];
    #pragma unroll
    for (int ci = 0; ci < 4; ++ci) {
        const float* p = base + (long)ci * spatial + (y0 + yl) * D + x0;
        float4 v = *(const float4*)p;
        stage[ci][yl][x0 >> 2] =
            q8(v.x) | (q8(v.y) << 8) | (q8(v.z) << 16) | (q8(v.w) << 24);
    }
    if (t < TPR) {                             // one extra row: y0+R (clamped)
        int ye = y0 + R; if (ye > D - 1) ye = D - 1;   // clamp == duplicate of
        #pragma unroll                                 // last row: matches y1
        for (int ci = 0; ci < 4; ++ci) {               // clamp semantics
            const float* p = base + (long)ci * spatial + ye * D + t * 4;
            float4 v = *(const float4*)p;
            stage[ci][R][t] =
                q8(v.x) | (q8(v.y) << 8) | (q8(v.z) << 16) | (q8(v.w) << 24);
        }
    }
    __syncthreads();

    int w = x0 >> 2;
    bool last = (x0 + 4 >= D);                 // row end: x+1 clamps to D-1
    uint4 e[4];
    #pragma unroll
    for (int ci = 0; ci < 4; ++ci) {
        unsigned wA0 = stage[ci][yl][w];
        unsigned wB0 = stage[ci][yl + 1][w];
        unsigned a4 = last ? (wA0 >> 24) : (stage[ci][yl][w + 1] & 0xffu);
        unsigned b4 = last ? (wB0 >> 24) : (stage[ci][yl + 1][w + 1] & 0xffu);
        unsigned a[5] = {wA0 & 0xffu, (wA0 >> 8) & 0xffu,
                         (wA0 >> 16) & 0xffu, wA0 >> 24, a4};
        unsigned bb[5] = {wB0 & 0xffu, (wB0 >> 8) & 0xffu,
                          (wB0 >> 16) & 0xffu, wB0 >> 24, b4};
        #pragma unroll
        for (int k = 0; k < 4; ++k) {
            ((unsigned*)&e[k])[ci] =
                a[k] | (a[k + 1] << 8) | (bb[k] << 16) | (bb[k + 1] << 24);
        }
    }

    // LDS transpose -> fully coalesced 16B/lane stores.
    __shared__ uint4 lds[4 * 257];
    #pragma unroll
    for (int j = 0; j < 4; ++j) lds[j * 257 + t] = e[j];
    __syncthreads();
    uint4* o = out + b * spatial + ((long)blockIdx.x << 10);
    #pragma unroll
    for (int k = 0; k < 4; ++k) {
        o[k * 256 + t] = lds[(t & 3) * 257 + k * 64 + (t >> 2)];
    }
}

// Repack with shfl neighbor fetch + LDS-staged COALESCED stores (fallback for
// D != 128 meeting the old validity conditions).
__global__ __launch_bounds__(256) void repack_u8x4_lds_kernel(
        const float* __restrict__ vol, uint4* __restrict__ out,
        long spatial, int D) {
    long chunk = (long)blockIdx.x * 256 + threadIdx.x;
    long b = blockIdx.y;
    long s = chunk << 2;
    int zs = D * D;
    int z = (int)(s / zs);
    int rem = (int)(s - (long)z * zs);
    int y = rem / D;
    int x0 = rem - y * D;           // chunk never straddles a row (D%4==0)
    int y1 = (y < D - 1) ? y + 1 : y;
    bool last = (x0 + 4 >= D);      // row-end: x+1 clamps to D-1 (= va.w)

    const float* base = vol + b * 4 * spatial;
    uint4 e[4];
    #pragma unroll
    for (int ci = 0; ci < 4; ++ci) {
        const float* pa = base + (long)ci * spatial + (long)z * zs + y * D + x0;
        const float* pb = base + (long)ci * spatial + (long)z * zs + y1 * D + x0;
        float4 va = *(const float4*)pa;
        float4 vb = *(const float4*)pb;
        float na_sh = __shfl_down(va.x, 1, 64);   // lane i+1's first element
        float nb_sh = __shfl_down(vb.x, 1, 64);
        float na = last ? va.w : na_sh;           // row-end lanes override (also
        float nb = last ? vb.w : nb_sh;           // covers wave-boundary lanes)
        float ra[5] = {va.x, va.y, va.z, va.w, na};
        float rb[5] = {vb.x, vb.y, vb.z, vb.w, nb};
        #pragma unroll
        for (int k = 0; k < 4; ++k) {
            unsigned d = q8(ra[k]) | (q8(ra[k + 1]) << 8) |
                         (q8(rb[k]) << 16) | (q8(rb[k + 1]) << 24);
            ((unsigned*)&e[k])[ci] = d;
        }
    }

    __shared__ uint4 lds[4 * 257];
    int t = threadIdx.x;
    #pragma unroll
    for (int j = 0; j < 4; ++j) lds[j * 257 + t] = e[j];
    __syncthreads();
    uint4* o = out + b * spatial + ((long)blockIdx.x << 10);
    #pragma unroll
    for (int k = 0; k < 4; ++k) {
        o[k * 256 + t] = lds[(t & 3) * 257 + k * 64 + (t >> 2)];
    }
}

// Fast repack without shfl/LDS (scalar neighbor loads). Requires D % 4 == 0.
__global__ __launch_bounds__(256) void repack_u8x4_kernel(const float* __restrict__ vol,
                                                          uint4* __restrict__ out,
                                                          long spatial, int D) {
    long chunk = (long)blockIdx.x * blockDim.x + threadIdx.x;
    long nchunks = spatial >> 2;
    if (chunk >= nchunks) return;
    long b = blockIdx.y;
    long s = chunk << 2;
    int zs = D * D;
    int z = (int)(s / zs);
    int rem = (int)(s - (long)z * zs);
    int y = rem / D;
    int x0 = rem - y * D;
    int y1 = (y < D - 1) ? y + 1 : y;

    const float* base = vol + b * 4 * spatial;
    uint4 e[4];
    #pragma unroll
    for (int ci = 0; ci < 4; ++ci) {
        const float* pa = base + (long)ci * spatial + (long)z * zs + y * D + x0;
        const float* pb = base + (long)ci * spatial + (long)z * zs + y1 * D + x0;
        float4 va = *(const float4*)pa;
        float4 vb = *(const float4*)pb;
        bool last = (x0 + 4 >= D);
        float na = last ? pa[3] : pa[4];
        float nb = last ? pb[3] : pb[4];
        float ra[5] = {va.x, va.y, va.z, va.w, na};
        float rb[5] = {vb.x, vb.y, vb.z, vb.w, nb};
        #pragma unroll
        for (int k = 0; k < 4; ++k) {
            unsigned d = q8(ra[k]) | (q8(ra[k + 1]) << 8) |
                         (q8(rb[k]) << 16) | (q8(rb[k + 1]) << 24);
            ((unsigned*)&e[k])[ci] = d;
        }
    }
    uint4* o = out + b * spatial + s;
    o[0] = e[0]; o[1] = e[1]; o[2] = e[2]; o[3] = e[3];
}

// Generic repack: one entry per thread (any D).
__global__ __launch_bounds__(256) void repack_u8_kernel(const float* __restrict__ vol,
                                                        uint4* __restrict__ out,
                                                        long total, long spatial, int D) {
    long idx = (long)blockIdx.x * blockDim.x + threadIdx.x;
    if (idx >= total) return;
    long b = idx / spatial;
    long s = idx - b * spatial;
    int zs = D * D;
    int z = (int)(s / zs);
    int rem = (int)(s - (long)z * zs);
    int y = rem / D;
    int x = rem - y * D;
    int x1 = (x < D - 1) ? x + 1 : x;
    int y1 = (y < D - 1) ? y + 1 : y;
    const float* base = vol + b * 4 * spatial;
    uint4 e;
    #pragma unroll
    for (int ci = 0; ci < 4; ++ci) {
        const float* p = base + (long)ci * spatial + (long)z * zs;
        unsigned d = q8(p[y * D + x]) | (q8(p[y * D + x1]) << 8) |
                     (q8(p[y1 * D + x]) << 16) | (q8(p[y1 * D + x1]) << 24);
        ((unsigned*)&e)[ci] = d;
    }
    out[idx] = e;
}

// ---------------- shared ray setup (bit-exact) ----------------

struct Ray {
    float posx, posy, posz;
    float stx, sty, stz;
    int n;   // conservative bound: steps >= n are provably invalid
};

__device__ __forceinline__ Ray ray_setup(const float* __restrict__ camrot,
                                         const float* __restrict__ campos,
                                         const float* __restrict__ focal,
                                         const float* __restrict__ princpt,
                                         const float* __restrict__ pixelcoords,
                                         int b, int y, int x, int H, int W) {
#pragma clang fp contract(off)
    long pidx = (((long)b * H + y) * W + x) * 2;
    float px = pixelcoords[pidx];
    float py = pixelcoords[pidx + 1];
    const float* R = camrot + b * 9;
    float cpx = campos[b * 3 + 0], cpy = campos[b * 3 + 1], cpz = campos[b * 3 + 2];
    float flx = focal[b * 2 + 0], fly = focal[b * 2 + 1];
    float prx = princpt[b * 2 + 0], pry = princpt[b * 2 + 1];

    float rx = (px - prx) / flx;
    float ry = (py - pry) / fly;
    float rz = 1.0f;
    float dx = R[0] * rx + R[3] * ry + R[6] * rz;
    float dy = R[1] * rx + R[4] * ry + R[7] * rz;
    float dz = R[2] * rx + R[5] * ry + R[8] * rz;
    float ss = dx * dx;
    ss = ss + dy * dy;
    ss = ss + dz * dz;
    float nrm = sqrtf(ss);
    dx = dx / nrm; dy = dy / nrm; dz = dz / nrm;

    float t1x = (-1.0f - cpx) / dx, t2x = (1.0f - cpx) / dx;
    float t1y = (-1.0f - cpy) / dy, t2y = (1.0f - cpy) / dy;
    float t1z = (-1.0f - cpz) / dz, t2z = (1.0f - cpz) / dz;
    float tmin = fmaxf(fminf(t1x, t2x), fmaxf(fminf(t1y, t2y), fminf(t1z, t2z)));
    float tmax = fminf(fmaxf(t1x, t2x), fminf(fmaxf(t1y, t2y), fmaxf(t1z, t2z)));
    bool hit = tmin < tmax;
    float t0 = fmaxf(hit ? tmin : 0.0f, 0.0f);

    Ray r;
    r.posx = cpx + dx * t0;
    r.posy = cpy + dy * t0;
    r.posz = cpz + dz * t0;
    r.stx = dx * DT; r.sty = dy * DT; r.stz = dz * DT;

    // valid step s needs t0 + s*DT < tmax; +4 slack dwarfs fp drift over <=111
    // rounded adds. NaN span -> fminf selects NSTEPS (conservative). Steps in
    // [n, NSTEPS) are provably invalid (mask would be 0) so skipping is exact.
    float span = (tmax - t0) * INV_DT + 4.0f;
    span = fminf(span, (float)NSTEPS);
    r.n = (hit && span > 0.0f) ? (int)span : 0;
    return r;
}

// ---------------- march: u8 stencil-pair volume + v_dot4 sampling ----------
// R14 structure: asm-pinned software pipeline (T3/T4 counted-vmcnt pattern).
// R2 counters showed the march latency-bound: VALUBusy 34%, occ 14%, HBM 26%,
// volume L3-resident (FETCH 80 MB < 134 MB volume). Addresses depend only on
// the position add-chain (never on loaded data) and index clamping makes any
// prefetch address in-bounds, so an issue-side chain runs 8 steps (2 chunks x
// 4 steps) ahead: per step it computes mask/weights/fz (bit-exact, identical
// add-chain) and issues 2 global_load_dwordx4 via inline asm (compiler cannot
// sink them - the R3/R4/R6/R10 collapse). s_waitcnt vmcnt(8) + sched_barrier
// before each chunk's consume keeps 8-16 loads in flight, never draining to 0
// in the loop (rule #18: sched_barrier after each asm wait).
// 16x16 blocks restored (8x8 regressed: worse L2 tile locality, R2 -7us).

#define ISTEP(C, u)                                                            \
    {                                                                          \
        bool inside = (ipx > -1.0f) && (ipx < 1.0f) && (ipy > -1.0f) &&        \
                      (ipy < 1.0f) && (ipz > -1.0f) && (ipz < 1.0f);           \
        C.m##u = inside ? 1.0f : 0.0f;                                         \
        float gx, gy, gz;                                                      \
        {                                                                      \
            _Pragma("clang fp contract(fast)")                                 \
            gx = ipx * gsc + gsc;                                              \
            gy = ipy * gsc + gsc;                                              \
            gz = ipz * gsc + gsc;                                              \
        }                                                                      \
        int ix = (int)gx; ix = min(max(ix, 0), D - 2);                         \
        int iy = (int)gy; iy = min(max(iy, 0), D - 2);                         \
        int iz = (int)gz; iz = min(max(iz, 0), D - 2);                         \
        float fx = gx - (float)ix;                                             \
        float fy = gy - (float)iy;                                             \
        C.fz##u = gz - (float)iz;                                              \
        unsigned wx1 = (unsigned)(int)(fx * 255.0f + 0.5f);                    \
        unsigned wy1 = (unsigned)(int)(fy * 255.0f + 0.5f);                    \
        unsigned wx0 = 255u - wx1, wy0 = 255u - wy1;                           \
        unsigned p00 = ((wx0 * wy0 + 128u) >> 8) & 0xffu;                      \
        unsigned p10 = ((wx1 * wy0 + 128u) >> 8) & 0xffu;                      \
        unsigned p01 = ((wx0 * wy1 + 128u) >> 8) & 0xffu;                      \
        unsigned p11 = ((wx1 * wy1 + 128u) >> 8) & 0xffu;                      \
        C.wp##u = p00 | (p10 << 8) | (p01 << 16) | (p11 << 24);                \
        unsigned voff = (unsigned)((iz * zs + iy * D + ix) << 4);              \
        asm volatile("global_load_dwordx4 %0, %2, %3\n\t"                      \
                     "global_load_dwordx4 %1, %2, %4"                          \
                     : "=&v"(C.A##u), "=&v"(C.B##u)                            \
                     : "v"(voff), "s"(vp), "s"(vpb)                            \
                     : "memory");                                              \
        ipx = ipx + stx; ipy = ipy + sty; ipz = ipz + stz;                     \
    }

#define CSTEP(C, u)                                                            \
    {                                                                          \
        unsigned wp = C.wp##u;                                                 \
        float rA = (float)udot4(C.A##u[0], wp), rB = (float)udot4(C.B##u[0], wp); \
        float gA = (float)udot4(C.A##u[1], wp), gB = (float)udot4(C.B##u[1], wp); \
        float bA = (float)udot4(C.A##u[2], wp), bB = (float)udot4(C.B##u[2], wp); \
        float sA = (float)udot4(C.A##u[3], wp), sB = (float)udot4(C.B##u[3], wp); \
        float fz = C.fz##u;                                                    \
        float rS, gS, bS, sw;                                                  \
        {                                                                      \
            _Pragma("clang fp contract(fast)")                                 \
            rS = rA + fz * (rB - rA);                                          \
            gS = gA + fz * (gB - gA);                                          \
            bS = bA + fz * (bB - bA);                                          \
            sw = (sA + fz * (sB - sA)) * inv;                                  \
        }                                                                      \
        float contrib = (fminf(alpha + sw * DT, 1.0f) - alpha) * C.m##u;       \
        {                                                                      \
            _Pragma("clang fp contract(fast)")                                 \
            accr = accr + rS * contrib;                                        \
            accg = accg + gS * contrib;                                        \
            accb = accb + bS * contrib;                                        \
        }                                                                      \
        alpha = alpha + contrib;                                               \
        pxx = pxx + stx; pyy = pyy + sty; pzz = pzz + stz;                     \
    }

#define ISSUE_CHUNK(C)   { ISTEP(C, 0) ISTEP(C, 1) ISTEP(C, 2) ISTEP(C, 3) }
#define CONSUME_CHUNK(C) { CSTEP(C, 0) CSTEP(C, 1) CSTEP(C, 2) CSTEP(C, 3) }

#define WAIT_VM8                                                               \
    asm volatile("s_waitcnt vmcnt(8)" ::: "memory");                           \
    __builtin_amdgcn_sched_barrier(0);
#define WAIT_VM0                                                               \
    asm volatile("s_waitcnt vmcnt(0)" ::: "memory");                           \
    __builtin_amdgcn_sched_barrier(0);

// Tail step (<=3 per ray): plain compiler-scheduled loads on the consume chain.
#define MARCH_TAIL_STEP                                                        \
    {                                                                          \
        bool inside = (pxx > -1.0f) && (pxx < 1.0f) && (pyy > -1.0f) &&        \
                      (pyy < 1.0f) && (pzz > -1.0f) && (pzz < 1.0f);           \
        float m = inside ? 1.0f : 0.0f;                                        \
        float gx, gy, gz;                                                      \
        {                                                                      \
            _Pragma("clang fp contract(fast)")                                 \
            gx = pxx * gsc + gsc;                                              \
            gy = pyy * gsc + gsc;                                              \
            gz = pzz * gsc + gsc;                                              \
        }                                                                      \
        int ix = (int)gx; ix = min(max(ix, 0), D - 2);                         \
        int iy = (int)gy; iy = min(max(iy, 0), D - 2);                         \
        int iz = (int)gz; iz = min(max(iz, 0), D - 2);                         \
        float fx = gx - (float)ix;                                             \
        float fy = gy - (float)iy;                                             \
        float fz = gz - (float)iz;                                             \
        unsigned wx1 = (unsigned)(int)(fx * 255.0f + 0.5f);                    \
        unsigned wy1 = (unsigned)(int)(fy * 255.0f + 0.5f);                    \
        unsigned wx0 = 255u - wx1, wy0 = 255u - wy1;                           \
        unsigned p00 = ((wx0 * wy0 + 128u) >> 8) & 0xffu;                      \
        unsigned p10 = ((wx1 * wy0 + 128u) >> 8) & 0xffu;                      \
        unsigned p01 = ((wx0 * wy1 + 128u) >> 8) & 0xffu;                      \
        unsigned p11 = ((wx1 * wy1 + 128u) >> 8) & 0xffu;                      \
        unsigned wp = p00 | (p10 << 8) | (p01 << 16) | (p11 << 24);            \
        const u32x4* p_ = vp + (iz * zs + iy * D + ix);                        \
        u32x4 A = p_[0];                                                       \
        u32x4 Bv = p_[zs];                                                     \
        float rA = (float)udot4(A[0], wp), rB = (float)udot4(Bv[0], wp);       \
        float gA = (float)udot4(A[1], wp), gB = (float)udot4(Bv[1], wp);       \
        float bA = (float)udot4(A[2], wp), bB = (float)udot4(Bv[2], wp);       \
        float sA = (float)udot4(A[3], wp), sB = (float)udot4(Bv[3], wp);       \
        float rS, gS, bS, sw;                                                  \
        {                                                                      \
            _Pragma("clang fp contract(fast)")                                 \
            rS = rA + fz * (rB - rA);                                          \
            gS = gA + fz * (gB - gA);                                          \
            bS = bA + fz * (bB - bA);                                          \
            sw = (sA + fz * (sB - sA)) * inv;                                  \
        }                                                                      \
        float contrib = (fminf(alpha + sw * DT, 1.0f) - alpha) * m;            \
        {                                                                      \
            _Pragma("clang fp contract(fast)")                                 \
            accr = accr + rS * contrib;                                        \
            accg = accg + gS * contrib;                                        \
            accb = accb + bS * contrib;                                        \
        }                                                                      \
        alpha = alpha + contrib;                                               \
        pxx = pxx + stx; pyy = pyy + sty; pzz = pzz + stz;                     \
    }

struct Chunk {
    u32x4 A0, A1, A2, A3, B0, B1, B2, B3;   // prefetched entries (asm-written)
    unsigned wp0, wp1, wp2, wp3;            // packed bilinear weights
    float fz0, fz1, fz2, fz3;               // z fraction
    float m0, m1, m2, m3;                   // validity mask (bit-exact chain)
};

template <int DD>
__global__ __launch_bounds__(256, 2) void raymarch_dot_kernel(
        const float* __restrict__ camrot, const float* __restrict__ campos,
        const float* __restrict__ focal, const float* __restrict__ princpt,
        const float* __restrict__ pixelcoords, const uint4* __restrict__ vol,
        float* __restrict__ out, int B, int H, int W, int Drt) {
#pragma clang fp contract(off)
    const int D = (DD > 0) ? DD : Drt;
    int x = blockIdx.x * 16 + threadIdx.x;
    int y = blockIdx.y * 16 + threadIdx.y;
    int b = blockIdx.z;
    if (x >= W || y >= H) return;

    Ray r = ray_setup(camrot, campos, focal, princpt, pixelcoords, b, y, x, H, W);

    float accr = 0.0f, accg = 0.0f, accb = 0.0f, alpha = 0.0f;
    const float gsc = 0.5f * (float)(D - 1);        // g = pos*gsc + gsc
    const float inv = 1.0f / (255.0f * 255.0f);
    const int zs = D * D;
    const u32x4* vp = (const u32x4*)vol + (long)b * ((long)zs * D);
    const u32x4* vpb = vp + zs;                      // z+1 plane base (SGPR)
    // consume chain (bit-exact reference chain) and issue chain (identical
    // add sequence, runs 8 steps ahead -> bit-identical values per step)
    float pxx = r.posx, pyy = r.posy, pzz = r.posz;
    float ipx = r.posx, ipy = r.posy, ipz = r.posz;
    float stx = r.stx, sty = r.sty, stz = r.stz;

    int nb = r.n & ~3;
    int chunks = nb >> 2;

    // zero the vmem counter so our asm bookkeeping starts clean
    WAIT_VM0;

    Chunk c0, c1;
    ISSUE_CHUNK(c0);                 // steps 0..3   (8 loads in flight)
    ISSUE_CHUNK(c1);                 // steps 4..7   (16 in flight)

    int k = 0;
    if (chunks > 0) {
        for (;;) {
            WAIT_VM8;                // c0's 8 loads done; c1's still in flight
            CONSUME_CHUNK(c0);
            ++k;
            if (alpha == 1.0f || k >= chunks) break;   // saturated / done
            ISSUE_CHUNK(c0);         // next chunk into freed buffer
            WAIT_VM8;
            CONSUME_CHUNK(c1);
            ++k;
            if (alpha == 1.0f || k >= chunks) break;
            ISSUE_CHUNK(c1);
        }
    }
    WAIT_VM0;                        // drain stragglers before tail/exit

    if (alpha != 1.0f) {
        for (int s = k << 2; s < r.n; ++s) { MARCH_TAIL_STEP; }
    }

    long hw = (long)H * W;
    long o = (long)b * 4 * hw + (long)y * W + x;
    out[o] = accr * inv;
    out[o + hw] = accg * inv;
    out[o + 2 * hw] = accb * inv;
    out[o + 3 * hw] = alpha;
}

// ---------------- fallback: whole-ray march on original fp32 layout ----------

__global__ __launch_bounds__(256) void raymarch_simple_kernel(
        const float* __restrict__ camrot, const float* __restrict__ campos,
        const float* __restrict__ focal, const float* __restrict__ princpt,
        const float* __restrict__ pixelcoords, const float* __restrict__ vol,
        float* __restrict__ out, int B, int H, int W, int D) {
#pragma clang fp contract(off)
    int x = blockIdx.x * blockDim.x + threadIdx.x;
    int y = blockIdx.y * blockDim.y + threadIdx.y;
    int b = blockIdx.z;
    if (x >= W || y >= H) return;

    Ray r = ray_setup(camrot, campos, focal, princpt, pixelcoords, b, y, x, H, W);

    float accr = 0.0f, accg = 0.0f, accb = 0.0f, alpha = 0.0f;
    float gmax = (float)(D - 1);
    long spatial = (long)D * D * D;
    long zstride = (long)D * D;
    const float* vb = vol + (long)b * 4 * spatial;
    float pxx = r.posx, pyy = r.posy, pzz = r.posz;

    for (int s = 0; s < r.n; ++s) {
        bool inside = (pxx > -1.0f) && (pxx < 1.0f) && (pyy > -1.0f) &&
                      (pyy < 1.0f) && (pzz > -1.0f) && (pzz < 1.0f);
        float m = inside ? 1.0f : 0.0f;
        float gx = fminf(fmaxf((pxx + 1.0f) * 0.5f * gmax, 0.0f), gmax);
        float gy = fminf(fmaxf((pyy + 1.0f) * 0.5f * gmax, 0.0f), gmax);
        float gz = fminf(fmaxf((pzz + 1.0f) * 0.5f * gmax, 0.0f), gmax);
        int ix0 = (int)floorf(gx); if (ix0 > D - 2) ix0 = D - 2;
        int iy0 = (int)floorf(gy); if (iy0 > D - 2) iy0 = D - 2;
        int iz0 = (int)floorf(gz); if (iz0 > D - 2) iz0 = D - 2;
        float fx = gx - (float)ix0;
        float fy = gy - (float)iy0;
        float fz = gz - (float)iz0;

        long s000 = (long)iz0 * zstride + (long)iy0 * D + ix0;
        float c[8][4];
        const long offs[8] = {s000, s000 + 1, s000 + D, s000 + D + 1,
                              s000 + zstride, s000 + zstride + 1,
                              s000 + zstride + D, s000 + zstride + D + 1};
        #pragma unroll
        for (int k = 0; k < 8; ++k) {
            c[k][0] = vb[offs[k]];
            c[k][1] = vb[offs[k] + spatial];
            c[k][2] = vb[offs[k] + 2 * spatial];
            c[k][3] = vb[offs[k] + 3 * spatial];
        }
        float wa = 1.0f - fx, wb = 1.0f - fy, wc = 1.0f - fz;
        float samp[4];
        #pragma unroll
        for (int ci = 0; ci < 4; ++ci) {
            float c00 = c[0][ci] * wa + c[1][ci] * fx;
            float c01 = c[2][ci] * wa + c[3][ci] * fx;
            float c10 = c[4][ci] * wa + c[5][ci] * fx;
            float c11 = c[6][ci] * wa + c[7][ci] * fx;
            float c0 = c00 * wb + c01 * fy;
            float c1 = c10 * wb + c11 * fy;
            samp[ci] = c0 * wc + c1 * fz;
        }
        float contrib = (fminf(alpha + samp[3] * DT, 1.0f) - alpha) * m;
        accr = accr + samp[0] * contrib;
        accg = accg + samp[1] * contrib;
        accb = accb + samp[2] * contrib;
        alpha = alpha + contrib;
        pxx = pxx + r.stx; pyy = pyy + r.sty; pzz = pzz + r.stz;
    }

    long hw = (long)H * W;
    long o = (long)b * 4 * hw + (long)y * W + x;
    out[o] = accr;
    out[o + hw] = accg;
    out[o + 2 * hw] = accb;
    out[o + 3 * hw] = alpha;
}

extern "C" void kernel_launch(void* const* d_in, const int* in_sizes, int n_in,
                              void* d_out, int out_size, void* d_ws, size_t ws_size,
                              hipStream_t stream) {
    const float* camrot = (const float*)d_in[0];
    const float* campos = (const float*)d_in[1];
    const float* focal = (const float*)d_in[2];
    const float* princpt = (const float*)d_in[3];
    const float* pixelcoords = (const float*)d_in[4];
    const float* volume = (const float*)d_in[5];
    float* out = (float*)d_out;

    int B = in_sizes[0] / 9;
    long spatial = (long)in_sizes[5] / (B * 4);  // D^3
    int D = (int)lround(cbrt((double)spatial));
    while ((long)D * D * D > spatial) D--;
    while ((long)(D + 1) * (D + 1) * (D + 1) <= spatial) D++;
    long hw = (long)in_sizes[4] / (B * 2);
    int H = (int)lround(sqrt((double)hw));
    int W = H;

    size_t vol_bytes = (size_t)B * spatial * sizeof(uint4);

    if (ws_size >= vol_bytes && D >= 2) {
        uint4* vol8 = (uint4*)d_ws;
        long nchunks = spatial >> 2;
        bool rowshare_ok = (D == 128) && ((nchunks % 256) == 0);
        bool lds_ok = ((D & 3) == 0) && ((64 % (D / 4)) == 0) &&
                      ((nchunks % 256) == 0);
        if (rowshare_ok) {
            dim3 rgrd((unsigned)(nchunks / 256), B, 1);
            repack_u8x4_rowshare_kernel<128><<<rgrd, dim3(256), 0, stream>>>(
                volume, vol8, spatial);
        } else if (lds_ok) {
            dim3 rgrd((unsigned)(nchunks / 256), B, 1);
            repack_u8x4_lds_kernel<<<rgrd, dim3(256), 0, stream>>>(volume, vol8,
                                                                   spatial, D);
        } else if ((D & 3) == 0) {
            dim3 rgrd((unsigned)((nchunks + 255) / 256), B, 1);
            repack_u8x4_kernel<<<rgrd, dim3(256), 0, stream>>>(volume, vol8, spatial, D);
        } else {
            long total = (long)B * spatial;
            repack_u8_kernel<<<dim3((unsigned)((total + 255) / 256)), dim3(256), 0,
                               stream>>>(volume, vol8, total, spatial, D);
        }
        dim3 blk(16, 16, 1);
        dim3 grd((W + 15) / 16, (H + 15) / 16, B);
        if (D == 128) {
            raymarch_dot_kernel<128><<<grd, blk, 0, stream>>>(
                camrot, campos, focal, princpt, pixelcoords, vol8, out, B, H, W, D);
        } else {
            raymarch_dot_kernel<0><<<grd, blk, 0, stream>>>(
                camrot, campos, focal, princpt, pixelcoords, vol8, out, B, H, W, D);
        }
    } else {
        dim3 blk(16, 16, 1);
        dim3 grd((W + 15) / 16, (H + 15) / 16, B);
        raymarch_simple_kernel<<<grd, blk, 0, stream>>>(camrot, campos, focal, princpt,
                                                        pixelcoords, volume,
                                                        out, B, H, W, D);
    }
}